// Round 1
// baseline (111.600 us; speedup 1.0000x reference)
//
#include <hip/hip_runtime.h>
#include <math.h>

// Problem constants (from reference): B=128, C=3, H=256, W=256, fp32.
#define BATCH 128
#define CHAN  3
#define IMH   256
#define IMW   256

// ---------------------------------------------------------------------------
// Kernel 1: per-batch affine matrix theta (2x3) -> ws[6*b .. 6*b+5]
// ---------------------------------------------------------------------------
__global__ void theta_kernel(const float* __restrict__ rot,
                             const float* __restrict__ trans,
                             const float* __restrict__ scale,
                             const float* __restrict__ shear,
                             float* __restrict__ theta) {
    int b = threadIdx.x;
    if (b >= BATCH) return;
    float r   = rot[b];
    float s   = scale[b];
    float c   = cosf(r);
    float sn  = sinf(r);
    float shx = shear[2 * b + 0];
    float shy = shear[2 * b + 1];
    theta[6 * b + 0] = s * (c - sn * shy);        // a00
    theta[6 * b + 1] = s * (c * shx - sn);        // a01
    theta[6 * b + 2] = trans[2 * b + 0];          // tx
    theta[6 * b + 3] = s * (sn + c * shy);        // a10
    theta[6 * b + 4] = s * (sn * shx + c);        // a11
    theta[6 * b + 5] = trans[2 * b + 1];          // ty
}

// ---------------------------------------------------------------------------
// Kernel 2: affine grid + bilinear sample, one thread per (b,h,w), loop c.
// blockDim.x = 256 = one output row => b,h wave-uniform; w = threadIdx.x.
// ---------------------------------------------------------------------------
__global__ __launch_bounds__(256) void affine_sample_kernel(
        const float* __restrict__ img,
        const float* __restrict__ theta,
        float* __restrict__ out) {
    const int w = threadIdx.x;          // 0..255
    const int h = blockIdx.x & (IMH - 1);
    const int b = blockIdx.x >> 8;      // 0..127  (uniform per block)

    // theta loads are block-uniform -> scalar loads
    const float* th = theta + 6 * b;
    const float a00 = th[0], a01 = th[1], tx = th[2];
    const float a10 = th[3], a11 = th[4], ty = th[5];

    // normalized output coords (align_corners=False style, per reference)
    const float gx = 2.0f * ((float)w + 0.5f) / (float)IMW - 1.0f;
    const float gy = 2.0f * ((float)h + 0.5f) / (float)IMH - 1.0f;

    const float gridx = a00 * gx + a01 * gy + tx;
    const float gridy = a10 * gx + a11 * gy + ty;

    // input-space continuous coords
    const float ix = ((gridx + 1.0f) * (float)IMW - 1.0f) * 0.5f;
    const float iy = ((gridy + 1.0f) * (float)IMH - 1.0f) * 0.5f;

    const float x0f = floorf(ix);
    const float y0f = floorf(iy);
    const float x1f = x0f + 1.0f;
    const float y1f = y0f + 1.0f;

    const float wx1 = ix - x0f;
    const float wx0 = 1.0f - wx1;
    const float wy1 = iy - y0f;
    const float wy0 = 1.0f - wy1;

    // validity uses the UNclipped float coords (reference semantics)
    const bool vx0 = (x0f >= 0.0f) & (x0f <= (float)(IMW - 1));
    const bool vx1 = (x1f >= 0.0f) & (x1f <= (float)(IMW - 1));
    const bool vy0 = (y0f >= 0.0f) & (y0f <= (float)(IMH - 1));
    const bool vy1 = (y1f >= 0.0f) & (y1f <= (float)(IMH - 1));

    // clipped integer indices
    const int x0 = min(max((int)x0f, 0), IMW - 1);
    const int x1 = min(max((int)x1f, 0), IMW - 1);
    const int y0 = min(max((int)y0f, 0), IMH - 1);
    const int y1 = min(max((int)y1f, 0), IMH - 1);

    const float w00 = (vx0 && vy0) ? (wx0 * wy0) : 0.0f;
    const float w10 = (vx1 && vy0) ? (wx1 * wy0) : 0.0f;
    const float w01 = (vx0 && vy1) ? (wx0 * wy1) : 0.0f;
    const float w11 = (vx1 && vy1) ? (wx1 * wy1) : 0.0f;

    const int i00 = y0 * IMW + x0;
    const int i10 = y0 * IMW + x1;
    const int i01 = y1 * IMW + x0;
    const int i11 = y1 * IMW + x1;

    const int plane = IMH * IMW;                 // 65536
    const int obase = (b * CHAN) * plane + h * IMW + w;
    const float* ibase = img + (size_t)(b * CHAN) * plane;

#pragma unroll
    for (int c = 0; c < CHAN; ++c) {
        const float* p = ibase + c * plane;
        float v = w00 * p[i00] + w10 * p[i10] + w01 * p[i01] + w11 * p[i11];
        out[obase + c * plane] = v;
    }
}

extern "C" void kernel_launch(void* const* d_in, const int* in_sizes, int n_in,
                              void* d_out, int out_size, void* d_ws, size_t ws_size,
                              hipStream_t stream) {
    const float* img   = (const float*)d_in[0];
    const float* rot   = (const float*)d_in[1];
    const float* trans = (const float*)d_in[2];
    const float* scale = (const float*)d_in[3];
    const float* shear = (const float*)d_in[4];
    float* out   = (float*)d_out;
    float* theta = (float*)d_ws;   // 128 * 6 floats = 3 KB scratch

    theta_kernel<<<1, BATCH, 0, stream>>>(rot, trans, scale, shear, theta);

    const int nblocks = BATCH * IMH;   // 32768 blocks x 256 threads
    affine_sample_kernel<<<nblocks, 256, 0, stream>>>(img, theta, out);
}

// Round 2
// 102.492 us; speedup vs baseline: 1.0889x; 1.0889x over previous
//
#include <hip/hip_runtime.h>
#include <math.h>

// Problem constants (from reference): B=128, C=3, H=256, W=256, fp32.
#define BATCH 128
#define CHAN  3
#define IMH   256
#define IMW   256
#define NXCD  8

// ---------------------------------------------------------------------------
// Kernel 1: per-batch affine matrix theta (2x3) -> ws[6*b .. 6*b+5]
// ---------------------------------------------------------------------------
__global__ void theta_kernel(const float* __restrict__ rot,
                             const float* __restrict__ trans,
                             const float* __restrict__ scale,
                             const float* __restrict__ shear,
                             float* __restrict__ theta) {
    int b = threadIdx.x;
    if (b >= BATCH) return;
    float r   = rot[b];
    float s   = scale[b];
    float c   = cosf(r);
    float sn  = sinf(r);
    float shx = shear[2 * b + 0];
    float shy = shear[2 * b + 1];
    theta[6 * b + 0] = s * (c - sn * shy);        // a00
    theta[6 * b + 1] = s * (c * shx - sn);        // a01
    theta[6 * b + 2] = trans[2 * b + 0];          // tx
    theta[6 * b + 3] = s * (sn + c * shy);        // a10
    theta[6 * b + 4] = s * (sn * shx + c);        // a11
    theta[6 * b + 5] = trans[2 * b + 1];          // ty
}

// ---------------------------------------------------------------------------
// Kernel 2: affine grid + bilinear sample, one thread per (b,h,w), loop c.
// Physical blockIdx p round-robins over XCDs (p % 8); remap to a logical
// block L = (p%8)*(NBLK/8) + p/8 so each XCD owns a CONTIGUOUS chunk of
// 4096 rows = 16 whole images -> each image's input fetched by ONE L2 only.
// ---------------------------------------------------------------------------
__global__ __launch_bounds__(256) void affine_sample_kernel(
        const float* __restrict__ img,
        const float* __restrict__ theta,
        float* __restrict__ out) {
    const int NBLK = BATCH * IMH;                  // 32768
    const int p = blockIdx.x;
    const int L = (p & (NXCD - 1)) * (NBLK / NXCD) + (p >> 3);  // chunked per-XCD

    const int w = threadIdx.x;          // 0..255
    const int h = L & (IMH - 1);
    const int b = L >> 8;               // 0..127  (uniform per block)

    // theta loads are block-uniform -> scalar loads
    const float* th = theta + 6 * b;
    const float a00 = th[0], a01 = th[1], tx = th[2];
    const float a10 = th[3], a11 = th[4], ty = th[5];

    // normalized output coords (per reference)
    const float gx = 2.0f * ((float)w + 0.5f) / (float)IMW - 1.0f;
    const float gy = 2.0f * ((float)h + 0.5f) / (float)IMH - 1.0f;

    const float gridx = a00 * gx + a01 * gy + tx;
    const float gridy = a10 * gx + a11 * gy + ty;

    // input-space continuous coords
    const float ix = ((gridx + 1.0f) * (float)IMW - 1.0f) * 0.5f;
    const float iy = ((gridy + 1.0f) * (float)IMH - 1.0f) * 0.5f;

    const float x0f = floorf(ix);
    const float y0f = floorf(iy);
    const float x1f = x0f + 1.0f;
    const float y1f = y0f + 1.0f;

    const float wx1 = ix - x0f;
    const float wx0 = 1.0f - wx1;
    const float wy1 = iy - y0f;
    const float wy0 = 1.0f - wy1;

    // validity uses the UNclipped float coords (reference semantics)
    const bool vx0 = (x0f >= 0.0f) & (x0f <= (float)(IMW - 1));
    const bool vx1 = (x1f >= 0.0f) & (x1f <= (float)(IMW - 1));
    const bool vy0 = (y0f >= 0.0f) & (y0f <= (float)(IMH - 1));
    const bool vy1 = (y1f >= 0.0f) & (y1f <= (float)(IMH - 1));

    // clipped integer indices
    const int x0 = min(max((int)x0f, 0), IMW - 1);
    const int x1 = min(max((int)x1f, 0), IMW - 1);
    const int y0 = min(max((int)y0f, 0), IMH - 1);
    const int y1 = min(max((int)y1f, 0), IMH - 1);

    const float w00 = (vx0 && vy0) ? (wx0 * wy0) : 0.0f;
    const float w10 = (vx1 && vy0) ? (wx1 * wy0) : 0.0f;
    const float w01 = (vx0 && vy1) ? (wx0 * wy1) : 0.0f;
    const float w11 = (vx1 && vy1) ? (wx1 * wy1) : 0.0f;

    const int i00 = y0 * IMW + x0;
    const int i10 = y0 * IMW + x1;
    const int i01 = y1 * IMW + x0;
    const int i11 = y1 * IMW + x1;

    const int plane = IMH * IMW;                 // 65536
    const int obase = (b * CHAN) * plane + h * IMW + w;
    const float* ibase = img + (size_t)(b * CHAN) * plane;

#pragma unroll
    for (int c = 0; c < CHAN; ++c) {
        const float* p2 = ibase + c * plane;
        float v = w00 * p2[i00] + w10 * p2[i10] + w01 * p2[i01] + w11 * p2[i11];
        // streamed output, never re-read: keep it out of L2 so input lines stay
        __builtin_nontemporal_store(v, &out[obase + c * plane]);
    }
}

extern "C" void kernel_launch(void* const* d_in, const int* in_sizes, int n_in,
                              void* d_out, int out_size, void* d_ws, size_t ws_size,
                              hipStream_t stream) {
    const float* img   = (const float*)d_in[0];
    const float* rot   = (const float*)d_in[1];
    const float* trans = (const float*)d_in[2];
    const float* scale = (const float*)d_in[3];
    const float* shear = (const float*)d_in[4];
    float* out   = (float*)d_out;
    float* theta = (float*)d_ws;   // 128 * 6 floats = 3 KB scratch

    theta_kernel<<<1, BATCH, 0, stream>>>(rot, trans, scale, shear, theta);

    const int nblocks = BATCH * IMH;   // 32768 blocks x 256 threads
    affine_sample_kernel<<<nblocks, 256, 0, stream>>>(img, theta, out);
}

// Round 3
// 99.286 us; speedup vs baseline: 1.1240x; 1.0323x over previous
//
#include <hip/hip_runtime.h>
#include <math.h>

// Problem constants (from reference): B=128, C=3, H=256, W=256, fp32.
#define BATCH 128
#define CHAN  3
#define IMH   256
#define IMW   256
#define NXCD  8
#define TW    16   // output tile width  (per block)
#define TH    16   // output tile height (per block)

// ---------------------------------------------------------------------------
// Kernel 1: per-batch affine matrix theta (2x3) -> ws[6*b .. 6*b+5]
// ---------------------------------------------------------------------------
__global__ void theta_kernel(const float* __restrict__ rot,
                             const float* __restrict__ trans,
                             const float* __restrict__ scale,
                             const float* __restrict__ shear,
                             float* __restrict__ theta) {
    int b = threadIdx.x;
    if (b >= BATCH) return;
    float r   = rot[b];
    float s   = scale[b];
    float c   = cosf(r);
    float sn  = sinf(r);
    float shx = shear[2 * b + 0];
    float shy = shear[2 * b + 1];
    theta[6 * b + 0] = s * (c - sn * shy);        // a00
    theta[6 * b + 1] = s * (c * shx - sn);        // a01
    theta[6 * b + 2] = trans[2 * b + 0];          // tx
    theta[6 * b + 3] = s * (sn + c * shy);        // a10
    theta[6 * b + 4] = s * (sn * shx + c);        // a11
    theta[6 * b + 5] = trans[2 * b + 1];          // ty
}

// ---------------------------------------------------------------------------
// Kernel 2: affine grid + bilinear sample.
// Block = 256 threads = one 16x16 OUTPUT TILE (not a 256x1 row):
//   local_w = t & 15, local_h = t >> 4  -> each wave is a 16x4 patch, so its
//   rotated input footprint spans ~12 rows x ~2 lines instead of ~64 rows.
//   Wave stores remain 4 full 64B lines (perfectly coalesced).
// XCD-chunked swizzle: each XCD owns 4096 consecutive logical blocks
//   = 16 whole images, so each image is fetched by exactly one L2.
// ---------------------------------------------------------------------------
__global__ __launch_bounds__(256) void affine_sample_kernel(
        const float* __restrict__ img,
        const float* __restrict__ theta,
        float* __restrict__ out) {
    const int NBLK = BATCH * (IMH / TH) * (IMW / TW);   // 32768
    const int p = blockIdx.x;
    const int L = (p & (NXCD - 1)) * (NBLK / NXCD) + (p >> 3);

    const int b    = L >> 8;          // 256 tiles per image
    const int tile = L & 255;
    const int ty   = tile >> 4;       // tile row    0..15
    const int tx   = tile & 15;       // tile column 0..15

    const int t = threadIdx.x;
    const int w = tx * TW + (t & (TW - 1));
    const int h = ty * TH + (t >> 4);

    // theta loads are block-uniform -> scalar loads
    const float* th = theta + 6 * b;
    const float a00 = th[0], a01 = th[1], txx = th[2];
    const float a10 = th[3], a11 = th[4], tyy = th[5];

    // normalized output coords (per reference)
    const float gx = 2.0f * ((float)w + 0.5f) / (float)IMW - 1.0f;
    const float gy = 2.0f * ((float)h + 0.5f) / (float)IMH - 1.0f;

    const float gridx = a00 * gx + a01 * gy + txx;
    const float gridy = a10 * gx + a11 * gy + tyy;

    // input-space continuous coords
    const float ix = ((gridx + 1.0f) * (float)IMW - 1.0f) * 0.5f;
    const float iy = ((gridy + 1.0f) * (float)IMH - 1.0f) * 0.5f;

    const float x0f = floorf(ix);
    const float y0f = floorf(iy);
    const float x1f = x0f + 1.0f;
    const float y1f = y0f + 1.0f;

    const float wx1 = ix - x0f;
    const float wx0 = 1.0f - wx1;
    const float wy1 = iy - y0f;
    const float wy0 = 1.0f - wy1;

    // validity uses the UNclipped float coords (reference semantics)
    const bool vx0 = (x0f >= 0.0f) & (x0f <= (float)(IMW - 1));
    const bool vx1 = (x1f >= 0.0f) & (x1f <= (float)(IMW - 1));
    const bool vy0 = (y0f >= 0.0f) & (y0f <= (float)(IMH - 1));
    const bool vy1 = (y1f >= 0.0f) & (y1f <= (float)(IMH - 1));

    // clipped integer indices
    const int x0 = min(max((int)x0f, 0), IMW - 1);
    const int x1 = min(max((int)x1f, 0), IMW - 1);
    const int y0 = min(max((int)y0f, 0), IMH - 1);
    const int y1 = min(max((int)y1f, 0), IMH - 1);

    const float w00 = (vx0 && vy0) ? (wx0 * wy0) : 0.0f;
    const float w10 = (vx1 && vy0) ? (wx1 * wy0) : 0.0f;
    const float w01 = (vx0 && vy1) ? (wx0 * wy1) : 0.0f;
    const float w11 = (vx1 && vy1) ? (wx1 * wy1) : 0.0f;

    const int i00 = y0 * IMW + x0;
    const int i10 = y0 * IMW + x1;
    const int i01 = y1 * IMW + x0;
    const int i11 = y1 * IMW + x1;

    const int plane = IMH * IMW;                 // 65536
    const int obase = (b * CHAN) * plane + h * IMW + w;
    const float* ibase = img + (size_t)(b * CHAN) * plane;

#pragma unroll
    for (int c = 0; c < CHAN; ++c) {
        const float* p2 = ibase + c * plane;
        float v = w00 * p2[i00] + w10 * p2[i10] + w01 * p2[i01] + w11 * p2[i11];
        // streamed output, never re-read: keep it out of L2 so input lines stay
        __builtin_nontemporal_store(v, &out[obase + c * plane]);
    }
}

extern "C" void kernel_launch(void* const* d_in, const int* in_sizes, int n_in,
                              void* d_out, int out_size, void* d_ws, size_t ws_size,
                              hipStream_t stream) {
    const float* img   = (const float*)d_in[0];
    const float* rot   = (const float*)d_in[1];
    const float* trans = (const float*)d_in[2];
    const float* scale = (const float*)d_in[3];
    const float* shear = (const float*)d_in[4];
    float* out   = (float*)d_out;
    float* theta = (float*)d_ws;   // 128 * 6 floats = 3 KB scratch

    theta_kernel<<<1, BATCH, 0, stream>>>(rot, trans, scale, shear, theta);

    const int nblocks = BATCH * (IMH / TH) * (IMW / TW);   // 32768
    affine_sample_kernel<<<nblocks, 256, 0, stream>>>(img, theta, out);
}